// Round 14
// baseline (129.732 us; speedup 1.0000x reference)
//
#include <hip/hip_runtime.h>

#define LOG2E 1.4426950408889634f
#define LN2   0.6931471805599453f
#define PSC   8.0f

typedef __attribute__((ext_vector_type(8))) short bf16x8;
typedef __attribute__((ext_vector_type(4))) float f32x4;
typedef __attribute__((ext_vector_type(4))) unsigned u32x4;

__device__ __forceinline__ unsigned pk_bf16(float lo, float hi){
  unsigned r;
  asm("v_cvt_pk_bf16_f32 %0, %1, %2" : "=v"(r) : "v"(lo), "v"(hi));
  return r;
}
// RNE f32->bf16 bit-ops (round-4-verified; position-unambiguous)
__device__ __forceinline__ unsigned short bf16_rne(float x){
  unsigned u = __float_as_uint(x);
  return (unsigned short)((u + 0x7FFFu + ((u>>16)&1u)) >> 16);
}

__device__ __forceinline__ float wave_sum64(float v){
#define DADD(ctrl) { int _t = __builtin_amdgcn_update_dpp(0, __float_as_int(v), ctrl, 0xF, 0xF, false); \
                     v = v + __int_as_float(_t); }
  DADD(0x111) DADD(0x112) DADD(0x114) DADD(0x118) DADD(0x142) DADD(0x143)
#undef DADD
  return __int_as_float(__builtin_amdgcn_readlane(__float_as_int(v), 63));
}
__device__ __forceinline__ float wave_max64(float v){
#define DMAX(ctrl) { int _t = __builtin_amdgcn_update_dpp(__float_as_int(v), __float_as_int(v), ctrl, 0xF, 0xF, false); \
                     v = fmaxf(v, __int_as_float(_t)); }
  DMAX(0x111) DMAX(0x112) DMAX(0x114) DMAX(0x118) DMAX(0x142) DMAX(0x143)
#undef DMAX
  return __int_as_float(__builtin_amdgcn_readlane(__float_as_int(v), 63));
}
__device__ __forceinline__ f32x4 vmax4(f32x4 a, f32x4 b){
  f32x4 r; r.x=fmaxf(a.x,b.x); r.y=fmaxf(a.y,b.y); r.z=fmaxf(a.z,b.z); r.w=fmaxf(a.w,b.w); return r;
}
__device__ __forceinline__ void wb(){
  __builtin_amdgcn_wave_barrier();
  asm volatile("" ::: "memory");
}

// Block = batch. Waves 0-3: consumers; wave c runs TWO interleaved 128-step
// chains (A: t in [256c,256c+128), B: [256c+128,256c+256)), each P = prod
// D(e)W^T via 4x4 MFMA accumulators. Waves 4-7: producers fill
// E[4][2buf][2half][16][64], double-buffered, __syncthreads per epoch.
// (r11-green structure; this round adds setprio around MFMA clusters and a
// merged two-chain renorm.) Epilogue: P bf16 to LDS; combine in wave 0.
__global__ void __launch_bounds__(512, 1)
patcrf_fwd(const float* __restrict__ le, const float* __restrict__ pe,
           const int* __restrict__ y, const float* __restrict__ lt,
           const int* __restrict__ t2l, const float* __restrict__ tp,
           const float* __restrict__ tc, const unsigned int* __restrict__ smask,
           float* __restrict__ out)
{
  const int b = blockIdx.x;
  const int tid = threadIdx.x;
  const int wv = tid >> 6;
  const int lane = tid & 63;
  const int bb = lane & 15, jj = lane >> 4;

  // phase1: trans[0,16K) | y[16K,20K) | E[20K,84K).  phase2: P bf16 [8][64][68] (69.6K)
  __shared__ __align__(16) char smem[86016];
  float* trans_lds = (float*)smem;
  int*   y_lds     = (int*)(smem + 16384);
  float* E_lds     = (float*)(smem + 20480);
  unsigned short* P_lds = (unsigned short*)smem;
  __shared__ __align__(16) float tp_lds[256];
  __shared__ __align__(16) float pf[64];
  __shared__ int   t2l_lds[64];
  __shared__ float scpart[8];
  __shared__ float L2arr[8];

  // ---- stage tables ----
  if (tid < 64){
    t2l_lds[tid] = t2l[tid];
    *(f32x4*)(tp_lds + tid*4) = *(const f32x4*)(tp + tid*4);
  }
  const int* yb = y + b*1024;
  y_lds[tid] = yb[tid];
  y_lds[tid+512] = yb[tid+512];
  __syncthreads();
  #pragma unroll
  for (int k=0;k<8;k++){
    int idx = k*512 + tid;
    trans_lds[idx] = lt[t2l_lds[idx>>6]*32 + t2l_lds[idx&63]] + tc[idx];
  }
  __syncthreads();

  const float* leb = le + (size_t)b*1024*32;
  const float* peb = pe + (size_t)b*1024*4;
  const int   myl  = t2l_lds[lane];
  const f32x4 mytp = *(const f32x4*)(tp_lds + lane*4);

  // ---- score phase: 2 positions per thread ----
  {
    int s0 = tid*2;
    int y0 = y_lds[s0], y1 = y_lds[s0+1];
    f32x4 pA = *(const f32x4*)(peb + (size_t)s0*4);
    f32x4 pB = *(const f32x4*)(peb + (size_t)(s0+1)*4);
    f32x4 tA = *(const f32x4*)(tp_lds + y0*4);
    f32x4 tB = *(const f32x4*)(tp_lds + y1*4);
    float s = leb[(size_t)s0*32 + t2l_lds[y0]]
            + pA.x*tA.x + pA.y*tA.y + pA.z*tA.z + pA.w*tA.w
            + leb[(size_t)(s0+1)*32 + t2l_lds[y1]]
            + pB.x*tB.x + pB.y*tB.y + pB.z*tB.z + pB.w*tB.w;
    s += trans_lds[y0*64 + y1];
    if (s0+2 < 1024) s += trans_lds[y1*64 + y_lds[s0+2]];
    float sw = wave_sum64(s);
    if (lane==0) scpart[wv] = sw;
  }

#define CSTEP(ACC, EPTR) do { \
    f32x4 ev[4]; \
    _Pragma("unroll") \
    for (int m_=0;m_<4;m_++) ev[m_] = *(const f32x4*)((EPTR) + 16*m_ + 4*jj); \
    u32x4 Bf[2][4]; \
    _Pragma("unroll") \
    for (int n_=0;n_<4;n_++){ \
      _Pragma("unroll") \
      for (int h_=0;h_<2;h_++){ \
        Bf[h_][n_] = (u32x4){ \
          pk_bf16(ACC[2*h_][n_].x,   ACC[2*h_][n_].y), \
          pk_bf16(ACC[2*h_][n_].z,   ACC[2*h_][n_].w), \
          pk_bf16(ACC[2*h_+1][n_].x, ACC[2*h_+1][n_].y), \
          pk_bf16(ACC[2*h_+1][n_].z, ACC[2*h_+1][n_].w) }; \
      } \
    } \
    __builtin_amdgcn_s_setprio(1); \
    _Pragma("unroll") \
    for (int m_=0;m_<4;m_++){ \
      _Pragma("unroll") \
      for (int n_=0;n_<4;n_++){ \
        f32x4 d_ = __builtin_amdgcn_mfma_f32_16x16x32_bf16( \
                     __builtin_bit_cast(bf16x8, Af[m_][0]), \
                     __builtin_bit_cast(bf16x8, Bf[0][n_]), zf, 0,0,0); \
        d_ = __builtin_amdgcn_mfma_f32_16x16x32_bf16( \
                     __builtin_bit_cast(bf16x8, Af[m_][1]), \
                     __builtin_bit_cast(bf16x8, Bf[1][n_]), d_, 0,0,0); \
        ACC[m_][n_] = d_ * ev[m_]; \
      } \
    } \
    __builtin_amdgcn_s_setprio(0); \
  } while(0)

  // merged renorm: one max over both chains, same pow2 scale applied to both,
  // exponent booked to both L2s (provably equivalent to independent renorms)
#define RENORM2(A1, A2, L1, L2V) do { \
    f32x4 m4_ = A1[0][0]; \
    _Pragma("unroll") \
    for (int m_=0;m_<4;m_++){ \
      _Pragma("unroll") \
      for (int n_=0;n_<4;n_++){ m4_ = vmax4(m4_, A1[m_][n_]); m4_ = vmax4(m4_, A2[m_][n_]); } \
    } \
    float mx_ = fmaxf(fmaxf(m4_.x,m4_.y), fmaxf(m4_.z,m4_.w)); \
    mx_ = wave_max64(mx_); \
    if (mx_ > 0.f){ \
      int Ex_ = (int)(__float_as_uint(mx_)>>23) - 127; \
      if (Ex_ != 0){ \
        float scl_ = __uint_as_float((unsigned)(127 - Ex_) << 23); \
        _Pragma("unroll") \
        for (int m_=0;m_<4;m_++){ \
          _Pragma("unroll") \
          for (int n_=0;n_<4;n_++){ A1[m_][n_] = A1[m_][n_]*scl_; A2[m_][n_] = A2[m_][n_]*scl_; } \
        } \
        (L1) += (float)Ex_; (L2V) += (float)Ex_; \
      } \
    } \
  } while(0)

  if (wv < 4){
    // ================= CONSUMER: two interleaved 128-step chains =============
    const int c = wv;
    u32x4 Af[4][2];
    #pragma unroll
    for (int m=0;m<4;m++){
      #pragma unroll
      for (int h=0;h<2;h++){
        unsigned uu[4];
        #pragma unroll
        for (int q=0;q<4;q++){
          int c0 = 2*q, c1 = 2*q+1;
          int sg0 = 32*h + ((c0>>2)<<4) + 4*jj + (c0&3);
          int sg1 = 32*h + ((c1>>2)<<4) + 4*jj + (c1&3);
          float w0 = __builtin_amdgcn_exp2f(trans_lds[sg0*64 + 16*m + bb]*LOG2E);
          float w1 = __builtin_amdgcn_exp2f(trans_lds[sg1*64 + 16*m + bb]*LOG2E);
          uu[q] = pk_bf16(w0, w1);
        }
        Af[m][h] = (u32x4){uu[0],uu[1],uu[2],uu[3]};
      }
    }
    f32x4 accA[4][4], accB[4][4];
    #pragma unroll
    for (int m=0;m<4;m++){
      #pragma unroll
      for (int n=0;n<4;n++){
        f32x4 z;
        z.x = (m==n && bb==4*jj+0) ? 1.f : 0.f;
        z.y = (m==n && bb==4*jj+1) ? 1.f : 0.f;
        z.z = (m==n && bb==4*jj+2) ? 1.f : 0.f;
        z.w = (m==n && bb==4*jj+3) ? 1.f : 0.f;
        accA[m][n] = z; accB[m][n] = z;
      }
    }
    float L2A = 0.f, L2B = 0.f;
    const f32x4 zf = {0.f,0.f,0.f,0.f};

    __syncthreads();   // E buf0 ready

    for (int ep=0; ep<8; ++ep){
      const float* EbA = E_lds + (c*4 + (ep&1)*2 + 0)*1024;
      const float* EbB = E_lds + (c*4 + (ep&1)*2 + 1)*1024;
      #pragma unroll 4
      for (int s=0;s<16;s++){
        if (!(c==0 && ep==0 && s==0)) CSTEP(accA, EbA + s*64);
        CSTEP(accB, EbB + s*64);
      }
      RENORM2(accA, accB, L2A, L2B);
      __syncthreads();
    }

    // P store: chain A -> chunk 2c, chain B -> chunk 2c+1 (phase-1 LDS dead)
    {
      unsigned short* PcA = P_lds + (2*c  )*4352;
      unsigned short* PcB = P_lds + (2*c+1)*4352;
      #pragma unroll
      for (int m=0;m<4;m++){
        #pragma unroll
        for (int n=0;n<4;n++){
          PcA[(16*m+4*jj+0)*68 + 16*n + bb] = bf16_rne(accA[m][n].x);
          PcA[(16*m+4*jj+1)*68 + 16*n + bb] = bf16_rne(accA[m][n].y);
          PcA[(16*m+4*jj+2)*68 + 16*n + bb] = bf16_rne(accA[m][n].z);
          PcA[(16*m+4*jj+3)*68 + 16*n + bb] = bf16_rne(accA[m][n].w);
          PcB[(16*m+4*jj+0)*68 + 16*n + bb] = bf16_rne(accB[m][n].x);
          PcB[(16*m+4*jj+1)*68 + 16*n + bb] = bf16_rne(accB[m][n].y);
          PcB[(16*m+4*jj+2)*68 + 16*n + bb] = bf16_rne(accB[m][n].z);
          PcB[(16*m+4*jj+3)*68 + 16*n + bb] = bf16_rne(accB[m][n].w);
        }
      }
      if (lane==0){ L2arr[2*c] = L2A; L2arr[2*c+1] = L2B; }
    }
  } else {
    // ================= PRODUCER: e(t) double-buffered epochs =================
    // wave 4+c serves consumer c: E[half h][step s] = e(256c + 128h + 16ep + s)
    const int c = wv - 4;
    const int base = 256*c;
    float leA[32]; f32x4 peA[32];
    // epoch 0 direct (buf 0): t = base + 128h + s, s<16
    #pragma unroll
    for (int k=0;k<32;k++){
      int t = base + 128*(k>>4) + (k&15);
      float l0 = leb[(size_t)t*32 + myl];
      f32x4 p0 = *(const f32x4*)(peb + (size_t)t*4);
      float x2 = (l0 + p0.x*mytp.x + p0.y*mytp.y + p0.z*mytp.z + p0.w*mytp.w)*LOG2E - PSC;
      E_lds[(c*4 + (k>>4))*1024 + (k&15)*64 + lane] = __builtin_amdgcn_exp2f(x2);
    }
    // raw epoch 1: t = base + 128h + 16 + s
    #pragma unroll
    for (int k=0;k<32;k++){
      int t = base + 128*(k>>4) + 16 + (k&15);
      leA[k] = leb[(size_t)t*32 + myl];
      peA[k] = *(const f32x4*)(peb + (size_t)t*4);
    }
    __syncthreads();   // E buf0 ready

    for (int ep=0; ep<8; ++ep){
      if (ep < 7){
        int buf = (ep+1)&1;
        #pragma unroll
        for (int k=0;k<32;k++){
          float x2 = (leA[k] + peA[k].x*mytp.x + peA[k].y*mytp.y
                             + peA[k].z*mytp.z + peA[k].w*mytp.w)*LOG2E - PSC;
          E_lds[(c*4 + buf*2 + (k>>4))*1024 + (k&15)*64 + lane] = __builtin_amdgcn_exp2f(x2);
        }
        if (ep < 6){
          // raw epoch ep+2: t = base + 128h + 16*(ep+2) + s  (max base+255)
          #pragma unroll
          for (int k=0;k<32;k++){
            int t = base + 128*(k>>4) + 16*(ep+2) + (k&15);
            leA[k] = leb[(size_t)t*32 + myl];
            peA[k] = *(const f32x4*)(peb + (size_t)t*4);
          }
        }
      }
      __syncthreads();
    }
  }

  __syncthreads();   // P + L2arr + scpart visible to all

  // ================= combine (wave 0) =================
  if (wv == 0){
    bool all01 = true, allf = true;
    #pragma unroll
    for (int k=0;k<16;k++){
      unsigned v = smask[k];
      all01 = all01 && (v <= 1u);
      allf  = allf  && (v == 0u || v == 0x3F800000u);
    }
    int startv;
    if (all01)      startv = ((const int*)smask)[lane];
    else if (allf)  startv = (((const unsigned*)smask)[lane] != 0u) ? 1 : 0;
    else            startv = ((const unsigned char*)smask)[lane];

    f32x4 pe0 = *(const f32x4*)peb;
    float x0 = leb[myl] + pe0.x*mytp.x + pe0.y*mytp.y + pe0.z*mytp.z + pe0.w*mytp.w;
    float v = startv ? __builtin_amdgcn_exp2f(x0*LOG2E - PSC) : 0.f;
    float L2p = 0.f;

    #pragma unroll 1
    for (int cc=0; cc<8; ++cc){
      pf[lane] = v;
      wb();
      const unsigned short* Pr = P_lds + cc*4352 + lane*68;   // own row
      float q = 0.f;
      #pragma unroll
      for (int k=0;k<16;k++){
        uint2 u = *(const uint2*)(Pr + 4*k);
        f32x4 vv = *(const f32x4*)(pf + 4*k);
        q = fmaf(__uint_as_float(u.x << 16),          vv.x, q);
        q = fmaf(__uint_as_float(u.x & 0xFFFF0000u),  vv.y, q);
        q = fmaf(__uint_as_float(u.y << 16),          vv.z, q);
        q = fmaf(__uint_as_float(u.y & 0xFFFF0000u),  vv.w, q);
      }
      wb();
      float S = wave_sum64(q);
      L2p += __builtin_amdgcn_logf(S);      // v_log_f32 = log2
      v = q * __builtin_amdgcn_rcpf(S);
    }
    if (lane == 0){
      float sct = ((scpart[0]+scpart[1])+(scpart[2]+scpart[3]))
                + ((scpart[4]+scpart[5])+(scpart[6]+scpart[7]));
      float l2t = ((L2arr[0]+L2arr[1])+(L2arr[2]+L2arr[3]))
                + ((L2arr[4]+L2arr[5])+(L2arr[6]+L2arr[7]));
      float logZ = LN2 * (l2t + L2p + PSC*1024.0f);
      out[b] = sct - logZ;
    }
  }
#undef CSTEP
#undef RENORM2
}

extern "C" void kernel_launch(void* const* d_in, const int* in_sizes, int n_in,
                              void* d_out, int out_size, void* d_ws, size_t ws_size,
                              hipStream_t stream)
{
  patcrf_fwd<<<256, 512, 0, stream>>>(
    (const float*)d_in[0],          // label_emissions [B,S,32]
    (const float*)d_in[1],          // pattern_emissions [B,S,4]
    (const int*)d_in[2],            // y [B,S]
    (const float*)d_in[3],          // label_transitions [32,32]
    (const int*)d_in[4],            // tag2label [64]
    (const float*)d_in[5],          // tag_patterns [64,4]
    (const float*)d_in[6],          // transition_constraints [64,64]
    (const unsigned int*)d_in[7],   // start_mask [64] (repr sniffed)
    (float*)d_out);
}

// Round 15
// 129.566 us; speedup vs baseline: 1.0013x; 1.0013x over previous
//
#include <hip/hip_runtime.h>

#define LOG2E 1.4426950408889634f
#define LN2   0.6931471805599453f
#define PSC   8.0f

typedef __attribute__((ext_vector_type(8))) short bf16x8;
typedef __attribute__((ext_vector_type(4))) float f32x4;
typedef __attribute__((ext_vector_type(4))) unsigned u32x4;

__device__ __forceinline__ unsigned pk_bf16(float lo, float hi){
  unsigned r;
  asm("v_cvt_pk_bf16_f32 %0, %1, %2" : "=v"(r) : "v"(lo), "v"(hi));
  return r;
}
// RNE f32->bf16 bit-ops (round-4-verified; position-unambiguous)
__device__ __forceinline__ unsigned short bf16_rne(float x){
  unsigned u = __float_as_uint(x);
  return (unsigned short)((u + 0x7FFFu + ((u>>16)&1u)) >> 16);
}

__device__ __forceinline__ float wave_sum64(float v){
#define DADD(ctrl) { int _t = __builtin_amdgcn_update_dpp(0, __float_as_int(v), ctrl, 0xF, 0xF, false); \
                     v = v + __int_as_float(_t); }
  DADD(0x111) DADD(0x112) DADD(0x114) DADD(0x118) DADD(0x142) DADD(0x143)
#undef DADD
  return __int_as_float(__builtin_amdgcn_readlane(__float_as_int(v), 63));
}
__device__ __forceinline__ float wave_max64(float v){
#define DMAX(ctrl) { int _t = __builtin_amdgcn_update_dpp(__float_as_int(v), __float_as_int(v), ctrl, 0xF, 0xF, false); \
                     v = fmaxf(v, __int_as_float(_t)); }
  DMAX(0x111) DMAX(0x112) DMAX(0x114) DMAX(0x118) DMAX(0x142) DMAX(0x143)
#undef DMAX
  return __int_as_float(__builtin_amdgcn_readlane(__float_as_int(v), 63));
}
__device__ __forceinline__ f32x4 vmax4(f32x4 a, f32x4 b){
  f32x4 r; r.x=fmaxf(a.x,b.x); r.y=fmaxf(a.y,b.y); r.z=fmaxf(a.z,b.z); r.w=fmaxf(a.w,b.w); return r;
}
__device__ __forceinline__ void wb(){
  __builtin_amdgcn_wave_barrier();
  asm volatile("" ::: "memory");
}

// Block = batch. Waves 0-3: consumers; wave c runs TWO interleaved 128-step
// chains (A: t in [256c,256c+128), B: [256c+128,256c+256)), each P = prod
// D(e)W^T via 4x4 MFMA accumulators. Waves 4-7: producers fill
// E[4][2buf][2half][16][64], double-buffered, __syncthreads per epoch.
// (r11-green structure + setprio around MFMA clusters — ONLY delta vs r11.)
// Epilogue: P bf16 to LDS; combine = 8 matvecs in wave 0.
__global__ void __launch_bounds__(512, 1)
patcrf_fwd(const float* __restrict__ le, const float* __restrict__ pe,
           const int* __restrict__ y, const float* __restrict__ lt,
           const int* __restrict__ t2l, const float* __restrict__ tp,
           const float* __restrict__ tc, const unsigned int* __restrict__ smask,
           float* __restrict__ out)
{
  const int b = blockIdx.x;
  const int tid = threadIdx.x;
  const int wv = tid >> 6;
  const int lane = tid & 63;
  const int bb = lane & 15, jj = lane >> 4;

  // phase1: trans[0,16K) | y[16K,20K) | E[20K,84K).  phase2: P bf16 [8][64][68] (69.6K)
  __shared__ __align__(16) char smem[86016];
  float* trans_lds = (float*)smem;
  int*   y_lds     = (int*)(smem + 16384);
  float* E_lds     = (float*)(smem + 20480);
  unsigned short* P_lds = (unsigned short*)smem;
  __shared__ __align__(16) float tp_lds[256];
  __shared__ __align__(16) float pf[64];
  __shared__ int   t2l_lds[64];
  __shared__ float scpart[8];
  __shared__ float L2arr[8];

  // ---- stage tables ----
  if (tid < 64){
    t2l_lds[tid] = t2l[tid];
    *(f32x4*)(tp_lds + tid*4) = *(const f32x4*)(tp + tid*4);
  }
  const int* yb = y + b*1024;
  y_lds[tid] = yb[tid];
  y_lds[tid+512] = yb[tid+512];
  __syncthreads();
  #pragma unroll
  for (int k=0;k<8;k++){
    int idx = k*512 + tid;
    trans_lds[idx] = lt[t2l_lds[idx>>6]*32 + t2l_lds[idx&63]] + tc[idx];
  }
  __syncthreads();

  const float* leb = le + (size_t)b*1024*32;
  const float* peb = pe + (size_t)b*1024*4;
  const int   myl  = t2l_lds[lane];
  const f32x4 mytp = *(const f32x4*)(tp_lds + lane*4);

  // ---- score phase: 2 positions per thread ----
  {
    int s0 = tid*2;
    int y0 = y_lds[s0], y1 = y_lds[s0+1];
    f32x4 pA = *(const f32x4*)(peb + (size_t)s0*4);
    f32x4 pB = *(const f32x4*)(peb + (size_t)(s0+1)*4);
    f32x4 tA = *(const f32x4*)(tp_lds + y0*4);
    f32x4 tB = *(const f32x4*)(tp_lds + y1*4);
    float s = leb[(size_t)s0*32 + t2l_lds[y0]]
            + pA.x*tA.x + pA.y*tA.y + pA.z*tA.z + pA.w*tA.w
            + leb[(size_t)(s0+1)*32 + t2l_lds[y1]]
            + pB.x*tB.x + pB.y*tB.y + pB.z*tB.z + pB.w*tB.w;
    s += trans_lds[y0*64 + y1];
    if (s0+2 < 1024) s += trans_lds[y1*64 + y_lds[s0+2]];
    float sw = wave_sum64(s);
    if (lane==0) scpart[wv] = sw;
  }

#define CSTEP(ACC, EPTR) do { \
    f32x4 ev[4]; \
    _Pragma("unroll") \
    for (int m_=0;m_<4;m_++) ev[m_] = *(const f32x4*)((EPTR) + 16*m_ + 4*jj); \
    u32x4 Bf[2][4]; \
    _Pragma("unroll") \
    for (int n_=0;n_<4;n_++){ \
      _Pragma("unroll") \
      for (int h_=0;h_<2;h_++){ \
        Bf[h_][n_] = (u32x4){ \
          pk_bf16(ACC[2*h_][n_].x,   ACC[2*h_][n_].y), \
          pk_bf16(ACC[2*h_][n_].z,   ACC[2*h_][n_].w), \
          pk_bf16(ACC[2*h_+1][n_].x, ACC[2*h_+1][n_].y), \
          pk_bf16(ACC[2*h_+1][n_].z, ACC[2*h_+1][n_].w) }; \
      } \
    } \
    __builtin_amdgcn_s_setprio(1); \
    _Pragma("unroll") \
    for (int m_=0;m_<4;m_++){ \
      _Pragma("unroll") \
      for (int n_=0;n_<4;n_++){ \
        f32x4 d_ = __builtin_amdgcn_mfma_f32_16x16x32_bf16( \
                     __builtin_bit_cast(bf16x8, Af[m_][0]), \
                     __builtin_bit_cast(bf16x8, Bf[0][n_]), zf, 0,0,0); \
        d_ = __builtin_amdgcn_mfma_f32_16x16x32_bf16( \
                     __builtin_bit_cast(bf16x8, Af[m_][1]), \
                     __builtin_bit_cast(bf16x8, Bf[1][n_]), d_, 0,0,0); \
        ACC[m_][n_] = d_ * ev[m_]; \
      } \
    } \
    __builtin_amdgcn_s_setprio(0); \
  } while(0)

#define RENORM(ACC, L2V) do { \
    f32x4 m4_ = ACC[0][0]; \
    _Pragma("unroll") \
    for (int m_=0;m_<4;m_++){ \
      _Pragma("unroll") \
      for (int n_=0;n_<4;n_++) m4_ = vmax4(m4_, ACC[m_][n_]); \
    } \
    float mx_ = fmaxf(fmaxf(m4_.x,m4_.y), fmaxf(m4_.z,m4_.w)); \
    mx_ = wave_max64(mx_); \
    if (mx_ > 0.f){ \
      int Ex_ = (int)(__float_as_uint(mx_)>>23) - 127; \
      if (Ex_ != 0){ \
        float scl_ = __uint_as_float((unsigned)(127 - Ex_) << 23); \
        _Pragma("unroll") \
        for (int m_=0;m_<4;m_++){ \
          _Pragma("unroll") \
          for (int n_=0;n_<4;n_++) ACC[m_][n_] = ACC[m_][n_]*scl_; \
        } \
        (L2V) += (float)Ex_; \
      } \
    } \
  } while(0)

  if (wv < 4){
    // ================= CONSUMER: two interleaved 128-step chains =============
    const int c = wv;
    u32x4 Af[4][2];
    #pragma unroll
    for (int m=0;m<4;m++){
      #pragma unroll
      for (int h=0;h<2;h++){
        unsigned uu[4];
        #pragma unroll
        for (int q=0;q<4;q++){
          int c0 = 2*q, c1 = 2*q+1;
          int sg0 = 32*h + ((c0>>2)<<4) + 4*jj + (c0&3);
          int sg1 = 32*h + ((c1>>2)<<4) + 4*jj + (c1&3);
          float w0 = __builtin_amdgcn_exp2f(trans_lds[sg0*64 + 16*m + bb]*LOG2E);
          float w1 = __builtin_amdgcn_exp2f(trans_lds[sg1*64 + 16*m + bb]*LOG2E);
          uu[q] = pk_bf16(w0, w1);
        }
        Af[m][h] = (u32x4){uu[0],uu[1],uu[2],uu[3]};
      }
    }
    f32x4 accA[4][4], accB[4][4];
    #pragma unroll
    for (int m=0;m<4;m++){
      #pragma unroll
      for (int n=0;n<4;n++){
        f32x4 z;
        z.x = (m==n && bb==4*jj+0) ? 1.f : 0.f;
        z.y = (m==n && bb==4*jj+1) ? 1.f : 0.f;
        z.z = (m==n && bb==4*jj+2) ? 1.f : 0.f;
        z.w = (m==n && bb==4*jj+3) ? 1.f : 0.f;
        accA[m][n] = z; accB[m][n] = z;
      }
    }
    float L2A = 0.f, L2B = 0.f;
    const f32x4 zf = {0.f,0.f,0.f,0.f};

    __syncthreads();   // E buf0 ready

    for (int ep=0; ep<8; ++ep){
      const float* EbA = E_lds + (c*4 + (ep&1)*2 + 0)*1024;
      const float* EbB = E_lds + (c*4 + (ep&1)*2 + 1)*1024;
      #pragma unroll 2
      for (int s=0;s<16;s++){
        if (!(c==0 && ep==0 && s==0)) CSTEP(accA, EbA + s*64);
        CSTEP(accB, EbB + s*64);
      }
      RENORM(accA, L2A);
      RENORM(accB, L2B);
      __syncthreads();
    }

    // P store: chain A -> chunk 2c, chain B -> chunk 2c+1 (phase-1 LDS dead)
    {
      unsigned short* PcA = P_lds + (2*c  )*4352;
      unsigned short* PcB = P_lds + (2*c+1)*4352;
      #pragma unroll
      for (int m=0;m<4;m++){
        #pragma unroll
        for (int n=0;n<4;n++){
          PcA[(16*m+4*jj+0)*68 + 16*n + bb] = bf16_rne(accA[m][n].x);
          PcA[(16*m+4*jj+1)*68 + 16*n + bb] = bf16_rne(accA[m][n].y);
          PcA[(16*m+4*jj+2)*68 + 16*n + bb] = bf16_rne(accA[m][n].z);
          PcA[(16*m+4*jj+3)*68 + 16*n + bb] = bf16_rne(accA[m][n].w);
          PcB[(16*m+4*jj+0)*68 + 16*n + bb] = bf16_rne(accB[m][n].x);
          PcB[(16*m+4*jj+1)*68 + 16*n + bb] = bf16_rne(accB[m][n].y);
          PcB[(16*m+4*jj+2)*68 + 16*n + bb] = bf16_rne(accB[m][n].z);
          PcB[(16*m+4*jj+3)*68 + 16*n + bb] = bf16_rne(accB[m][n].w);
        }
      }
      if (lane==0){ L2arr[2*c] = L2A; L2arr[2*c+1] = L2B; }
    }
  } else {
    // ================= PRODUCER: e(t) double-buffered epochs =================
    // wave 4+c serves consumer c: E[half h][step s] = e(256c + 128h + 16ep + s)
    const int c = wv - 4;
    const int base = 256*c;
    float leA[32]; f32x4 peA[32];
    // epoch 0 direct (buf 0): t = base + 128h + s, s<16
    #pragma unroll
    for (int k=0;k<32;k++){
      int t = base + 128*(k>>4) + (k&15);
      float l0 = leb[(size_t)t*32 + myl];
      f32x4 p0 = *(const f32x4*)(peb + (size_t)t*4);
      float x2 = (l0 + p0.x*mytp.x + p0.y*mytp.y + p0.z*mytp.z + p0.w*mytp.w)*LOG2E - PSC;
      E_lds[(c*4 + (k>>4))*1024 + (k&15)*64 + lane] = __builtin_amdgcn_exp2f(x2);
    }
    // raw epoch 1: t = base + 128h + 16 + s
    #pragma unroll
    for (int k=0;k<32;k++){
      int t = base + 128*(k>>4) + 16 + (k&15);
      leA[k] = leb[(size_t)t*32 + myl];
      peA[k] = *(const f32x4*)(peb + (size_t)t*4);
    }
    __syncthreads();   // E buf0 ready

    for (int ep=0; ep<8; ++ep){
      if (ep < 7){
        int buf = (ep+1)&1;
        #pragma unroll
        for (int k=0;k<32;k++){
          float x2 = (leA[k] + peA[k].x*mytp.x + peA[k].y*mytp.y
                             + peA[k].z*mytp.z + peA[k].w*mytp.w)*LOG2E - PSC;
          E_lds[(c*4 + buf*2 + (k>>4))*1024 + (k&15)*64 + lane] = __builtin_amdgcn_exp2f(x2);
        }
        if (ep < 6){
          // raw epoch ep+2: t = base + 128h + 16*(ep+2) + s  (max base+255)
          #pragma unroll
          for (int k=0;k<32;k++){
            int t = base + 128*(k>>4) + 16*(ep+2) + (k&15);
            leA[k] = leb[(size_t)t*32 + myl];
            peA[k] = *(const f32x4*)(peb + (size_t)t*4);
          }
        }
      }
      __syncthreads();
    }
  }

  __syncthreads();   // P + L2arr + scpart visible to all

  // ================= combine (wave 0) =================
  if (wv == 0){
    bool all01 = true, allf = true;
    #pragma unroll
    for (int k=0;k<16;k++){
      unsigned v = smask[k];
      all01 = all01 && (v <= 1u);
      allf  = allf  && (v == 0u || v == 0x3F800000u);
    }
    int startv;
    if (all01)      startv = ((const int*)smask)[lane];
    else if (allf)  startv = (((const unsigned*)smask)[lane] != 0u) ? 1 : 0;
    else            startv = ((const unsigned char*)smask)[lane];

    f32x4 pe0 = *(const f32x4*)peb;
    float x0 = leb[myl] + pe0.x*mytp.x + pe0.y*mytp.y + pe0.z*mytp.z + pe0.w*mytp.w;
    float v = startv ? __builtin_amdgcn_exp2f(x0*LOG2E - PSC) : 0.f;
    float L2p = 0.f;

    #pragma unroll 1
    for (int cc=0; cc<8; ++cc){
      pf[lane] = v;
      wb();
      const unsigned short* Pr = P_lds + cc*4352 + lane*68;   // own row
      float q = 0.f;
      #pragma unroll
      for (int k=0;k<16;k++){
        uint2 u = *(const uint2*)(Pr + 4*k);
        f32x4 vv = *(const f32x4*)(pf + 4*k);
        q = fmaf(__uint_as_float(u.x << 16),          vv.x, q);
        q = fmaf(__uint_as_float(u.x & 0xFFFF0000u),  vv.y, q);
        q = fmaf(__uint_as_float(u.y << 16),          vv.z, q);
        q = fmaf(__uint_as_float(u.y & 0xFFFF0000u),  vv.w, q);
      }
      wb();
      float S = wave_sum64(q);
      L2p += __builtin_amdgcn_logf(S);      // v_log_f32 = log2
      v = q * __builtin_amdgcn_rcpf(S);
    }
    if (lane == 0){
      float sct = ((scpart[0]+scpart[1])+(scpart[2]+scpart[3]))
                + ((scpart[4]+scpart[5])+(scpart[6]+scpart[7]));
      float l2t = ((L2arr[0]+L2arr[1])+(L2arr[2]+L2arr[3]))
                + ((L2arr[4]+L2arr[5])+(L2arr[6]+L2arr[7]));
      float logZ = LN2 * (l2t + L2p + PSC*1024.0f);
      out[b] = sct - logZ;
    }
  }
#undef CSTEP
#undef RENORM
}

extern "C" void kernel_launch(void* const* d_in, const int* in_sizes, int n_in,
                              void* d_out, int out_size, void* d_ws, size_t ws_size,
                              hipStream_t stream)
{
  patcrf_fwd<<<256, 512, 0, stream>>>(
    (const float*)d_in[0],          // label_emissions [B,S,32]
    (const float*)d_in[1],          // pattern_emissions [B,S,4]
    (const int*)d_in[2],            // y [B,S]
    (const float*)d_in[3],          // label_transitions [32,32]
    (const int*)d_in[4],            // tag2label [64]
    (const float*)d_in[5],          // tag_patterns [64,4]
    (const float*)d_in[6],          // transition_constraints [64,64]
    (const unsigned int*)d_in[7],   // start_mask [64] (repr sniffed)
    (float*)d_out);
}

// Round 16
// 119.347 us; speedup vs baseline: 1.0870x; 1.0856x over previous
//
#include <hip/hip_runtime.h>

#define LOG2E 1.4426950408889634f
#define LN2   0.6931471805599453f
#define PSC   8.0f

typedef __attribute__((ext_vector_type(8))) short bf16x8;
typedef __attribute__((ext_vector_type(4))) float f32x4;
typedef __attribute__((ext_vector_type(4))) unsigned u32x4;

__device__ __forceinline__ unsigned pk_bf16(float lo, float hi){
  unsigned r;
  asm("v_cvt_pk_bf16_f32 %0, %1, %2" : "=v"(r) : "v"(lo), "v"(hi));
  return r;
}
// RNE f32->bf16 bit-ops (round-4-verified formula; position-unambiguous)
__device__ __forceinline__ unsigned short bf16_rne(float x){
  unsigned u = __float_as_uint(x);
  return (unsigned short)((u + 0x7FFFu + ((u>>16)&1u)) >> 16);
}

__device__ __forceinline__ float wave_sum64(float v){
#define DADD(ctrl) { int _t = __builtin_amdgcn_update_dpp(0, __float_as_int(v), ctrl, 0xF, 0xF, false); \
                     v = v + __int_as_float(_t); }
  DADD(0x111) DADD(0x112) DADD(0x114) DADD(0x118) DADD(0x142) DADD(0x143)
#undef DADD
  return __int_as_float(__builtin_amdgcn_readlane(__float_as_int(v), 63));
}
__device__ __forceinline__ float wave_max64(float v){
#define DMAX(ctrl) { int _t = __builtin_amdgcn_update_dpp(__float_as_int(v), __float_as_int(v), ctrl, 0xF, 0xF, false); \
                     v = fmaxf(v, __int_as_float(_t)); }
  DMAX(0x111) DMAX(0x112) DMAX(0x114) DMAX(0x118) DMAX(0x142) DMAX(0x143)
#undef DMAX
  return __int_as_float(__builtin_amdgcn_readlane(__float_as_int(v), 63));
}
__device__ __forceinline__ f32x4 vmax4(f32x4 a, f32x4 b){
  f32x4 r; r.x=fmaxf(a.x,b.x); r.y=fmaxf(a.y,b.y); r.z=fmaxf(a.z,b.z); r.w=fmaxf(a.w,b.w); return r;
}

// Block = batch. Waves 0-3: consumers; wave c runs TWO interleaved 128-step
// chains (A: t in [256c,256c+128), B: [256c+128,256c+256)), each P = prod
// D(e)W^T via 4x4 MFMA accumulators (r7-verified datapath). Waves 4-7:
// producers fill E[4][2buf][2half][16][64], double-buffered, __syncthreads
// per epoch (r7-verified). 8 epochs x 16 steps per chain.
// Epilogue: P bf16 to LDS; combine = 8 matvecs in wave 0.
// (r11 byte-for-byte — session-best green kernel, 119us.)
__global__ void __launch_bounds__(512, 1)
patcrf_fwd(const float* __restrict__ le, const float* __restrict__ pe,
           const int* __restrict__ y, const float* __restrict__ lt,
           const int* __restrict__ t2l, const float* __restrict__ tp,
           const float* __restrict__ tc, const unsigned int* __restrict__ smask,
           float* __restrict__ out)
{
  const int b = blockIdx.x;
  const int tid = threadIdx.x;
  const int wv = tid >> 6;
  const int lane = tid & 63;
  const int bb = lane & 15, jj = lane >> 4;

  // phase1: trans[0,16K) | y[16K,20K) | E[20K,84K).  phase2: P bf16 [8][64][68] (69.6K)
  __shared__ __align__(16) char smem[86016];
  float* trans_lds = (float*)smem;
  int*   y_lds     = (int*)(smem + 16384);
  float* E_lds     = (float*)(smem + 20480);
  unsigned short* P_lds = (unsigned short*)smem;
  __shared__ __align__(16) float tp_lds[256];
  __shared__ __align__(16) float pf[64];
  __shared__ int   t2l_lds[64];
  __shared__ float scpart[8];
  __shared__ float L2arr[8];

  // ---- stage tables ----
  if (tid < 64){
    t2l_lds[tid] = t2l[tid];
    *(f32x4*)(tp_lds + tid*4) = *(const f32x4*)(tp + tid*4);
  }
  const int* yb = y + b*1024;
  y_lds[tid] = yb[tid];
  y_lds[tid+512] = yb[tid+512];
  __syncthreads();
  #pragma unroll
  for (int k=0;k<8;k++){
    int idx = k*512 + tid;
    trans_lds[idx] = lt[t2l_lds[idx>>6]*32 + t2l_lds[idx&63]] + tc[idx];
  }
  __syncthreads();

  const float* leb = le + (size_t)b*1024*32;
  const float* peb = pe + (size_t)b*1024*4;
  const int   myl  = t2l_lds[lane];
  const f32x4 mytp = *(const f32x4*)(tp_lds + lane*4);

  // ---- score phase: 2 positions per thread ----
  {
    int s0 = tid*2;
    int y0 = y_lds[s0], y1 = y_lds[s0+1];
    f32x4 pA = *(const f32x4*)(peb + (size_t)s0*4);
    f32x4 pB = *(const f32x4*)(peb + (size_t)(s0+1)*4);
    f32x4 tA = *(const f32x4*)(tp_lds + y0*4);
    f32x4 tB = *(const f32x4*)(tp_lds + y1*4);
    float s = leb[(size_t)s0*32 + t2l_lds[y0]]
            + pA.x*tA.x + pA.y*tA.y + pA.z*tA.z + pA.w*tA.w
            + leb[(size_t)(s0+1)*32 + t2l_lds[y1]]
            + pB.x*tB.x + pB.y*tB.y + pB.z*tB.z + pB.w*tB.w;
    s += trans_lds[y0*64 + y1];
    if (s0+2 < 1024) s += trans_lds[y1*64 + y_lds[s0+2]];
    float sw = wave_sum64(s);
    if (lane==0) scpart[wv] = sw;
  }

#define CSTEP(ACC, EPTR) do { \
    f32x4 ev[4]; \
    _Pragma("unroll") \
    for (int m_=0;m_<4;m_++) ev[m_] = *(const f32x4*)((EPTR) + 16*m_ + 4*jj); \
    u32x4 Bf[2][4]; \
    _Pragma("unroll") \
    for (int n_=0;n_<4;n_++){ \
      _Pragma("unroll") \
      for (int h_=0;h_<2;h_++){ \
        Bf[h_][n_] = (u32x4){ \
          pk_bf16(ACC[2*h_][n_].x,   ACC[2*h_][n_].y), \
          pk_bf16(ACC[2*h_][n_].z,   ACC[2*h_][n_].w), \
          pk_bf16(ACC[2*h_+1][n_].x, ACC[2*h_+1][n_].y), \
          pk_bf16(ACC[2*h_+1][n_].z, ACC[2*h_+1][n_].w) }; \
      } \
    } \
    _Pragma("unroll") \
    for (int m_=0;m_<4;m_++){ \
      _Pragma("unroll") \
      for (int n_=0;n_<4;n_++){ \
        f32x4 d_ = __builtin_amdgcn_mfma_f32_16x16x32_bf16( \
                     __builtin_bit_cast(bf16x8, Af[m_][0]), \
                     __builtin_bit_cast(bf16x8, Bf[0][n_]), zf, 0,0,0); \
        d_ = __builtin_amdgcn_mfma_f32_16x16x32_bf16( \
                     __builtin_bit_cast(bf16x8, Af[m_][1]), \
                     __builtin_bit_cast(bf16x8, Bf[1][n_]), d_, 0,0,0); \
        ACC[m_][n_] = d_ * ev[m_]; \
      } \
    } \
  } while(0)

#define RENORM(ACC, L2V) do { \
    f32x4 m4_ = ACC[0][0]; \
    _Pragma("unroll") \
    for (int m_=0;m_<4;m_++){ \
      _Pragma("unroll") \
      for (int n_=0;n_<4;n_++) m4_ = vmax4(m4_, ACC[m_][n_]); \
    } \
    float mx_ = fmaxf(fmaxf(m4_.x,m4_.y), fmaxf(m4_.z,m4_.w)); \
    mx_ = wave_max64(mx_); \
    if (mx_ > 0.f){ \
      int Ex_ = (int)(__float_as_uint(mx_)>>23) - 127; \
      if (Ex_ != 0){ \
        float scl_ = __uint_as_float((unsigned)(127 - Ex_) << 23); \
        _Pragma("unroll") \
        for (int m_=0;m_<4;m_++){ \
          _Pragma("unroll") \
          for (int n_=0;n_<4;n_++) ACC[m_][n_] = ACC[m_][n_]*scl_; \
        } \
        (L2V) += (float)Ex_; \
      } \
    } \
  } while(0)

  if (wv < 4){
    // ================= CONSUMER: two interleaved 128-step chains =============
    const int c = wv;
    u32x4 Af[4][2];
    #pragma unroll
    for (int m=0;m<4;m++){
      #pragma unroll
      for (int h=0;h<2;h++){
        unsigned uu[4];
        #pragma unroll
        for (int q=0;q<4;q++){
          int c0 = 2*q, c1 = 2*q+1;
          int sg0 = 32*h + ((c0>>2)<<4) + 4*jj + (c0&3);
          int sg1 = 32*h + ((c1>>2)<<4) + 4*jj + (c1&3);
          float w0 = __builtin_amdgcn_exp2f(trans_lds[sg0*64 + 16*m + bb]*LOG2E);
          float w1 = __builtin_amdgcn_exp2f(trans_lds[sg1*64 + 16*m + bb]*LOG2E);
          uu[q] = pk_bf16(w0, w1);
        }
        Af[m][h] = (u32x4){uu[0],uu[1],uu[2],uu[3]};
      }
    }
    f32x4 accA[4][4], accB[4][4];
    #pragma unroll
    for (int m=0;m<4;m++){
      #pragma unroll
      for (int n=0;n<4;n++){
        f32x4 z;
        z.x = (m==n && bb==4*jj+0) ? 1.f : 0.f;
        z.y = (m==n && bb==4*jj+1) ? 1.f : 0.f;
        z.z = (m==n && bb==4*jj+2) ? 1.f : 0.f;
        z.w = (m==n && bb==4*jj+3) ? 1.f : 0.f;
        accA[m][n] = z; accB[m][n] = z;
      }
    }
    float L2A = 0.f, L2B = 0.f;
    const f32x4 zf = {0.f,0.f,0.f,0.f};

    __syncthreads();   // E buf0 ready

    for (int ep=0; ep<8; ++ep){
      const float* EbA = E_lds + (c*4 + (ep&1)*2 + 0)*1024;
      const float* EbB = E_lds + (c*4 + (ep&1)*2 + 1)*1024;
      #pragma unroll 2
      for (int s=0;s<16;s++){
        if (!(c==0 && ep==0 && s==0)) CSTEP(accA, EbA + s*64);
        CSTEP(accB, EbB + s*64);
      }
      RENORM(accA, L2A);
      RENORM(accB, L2B);
      __syncthreads();
    }

    // P store: chain A -> chunk 2c, chain B -> chunk 2c+1 (phase-1 LDS dead)
    {
      unsigned short* PcA = P_lds + (2*c  )*4352;
      unsigned short* PcB = P_lds + (2*c+1)*4352;
      #pragma unroll
      for (int m=0;m<4;m++){
        #pragma unroll
        for (int n=0;n<4;n++){
          PcA[(16*m+4*jj+0)*68 + 16*n + bb] = bf16_rne(accA[m][n].x);
          PcA[(16*m+4*jj+1)*68 + 16*n + bb] = bf16_rne(accA[m][n].y);
          PcA[(16*m+4*jj+2)*68 + 16*n + bb] = bf16_rne(accA[m][n].z);
          PcA[(16*m+4*jj+3)*68 + 16*n + bb] = bf16_rne(accA[m][n].w);
          PcB[(16*m+4*jj+0)*68 + 16*n + bb] = bf16_rne(accB[m][n].x);
          PcB[(16*m+4*jj+1)*68 + 16*n + bb] = bf16_rne(accB[m][n].y);
          PcB[(16*m+4*jj+2)*68 + 16*n + bb] = bf16_rne(accB[m][n].z);
          PcB[(16*m+4*jj+3)*68 + 16*n + bb] = bf16_rne(accB[m][n].w);
        }
      }
      if (lane==0){ L2arr[2*c] = L2A; L2arr[2*c+1] = L2B; }
    }
  } else {
    // ================= PRODUCER: e(t) double-buffered epochs =================
    // wave 4+c serves consumer c: E[half h][step s] = e(256c + 128h + 16ep + s)
    const int c = wv - 4;
    const int base = 256*c;
    float leA[32]; f32x4 peA[32];
    // epoch 0 direct (buf 0): t = base + 128h + s, s<16
    #pragma unroll
    for (int k=0;k<32;k++){
      int t = base + 128*(k>>4) + (k&15);
      float l0 = leb[(size_t)t*32 + myl];
      f32x4 p0 = *(const f32x4*)(peb + (size_t)t*4);
      float x2 = (l0 + p0.x*mytp.x + p0.y*mytp.y + p0.z*mytp.z + p0.w*mytp.w)*LOG2E - PSC;
      E_lds[(c*4 + (k>>4))*1024 + (k&15)*64 + lane] = __builtin_amdgcn_exp2f(x2);
    }
    // raw epoch 1: t = base + 128h + 16 + s
    #pragma unroll
    for (int k=0;k<32;k++){
      int t = base + 128*(k>>4) + 16 + (k&15);
      leA[k] = leb[(size_t)t*32 + myl];
      peA[k] = *(const f32x4*)(peb + (size_t)t*4);
    }
    __syncthreads();   // E buf0 ready

    for (int ep=0; ep<8; ++ep){
      if (ep < 7){
        int buf = (ep+1)&1;
        #pragma unroll
        for (int k=0;k<32;k++){
          float x2 = (leA[k] + peA[k].x*mytp.x + peA[k].y*mytp.y
                             + peA[k].z*mytp.z + peA[k].w*mytp.w)*LOG2E - PSC;
          E_lds[(c*4 + buf*2 + (k>>4))*1024 + (k&15)*64 + lane] = __builtin_amdgcn_exp2f(x2);
        }
        if (ep < 6){
          // raw epoch ep+2: t = base + 128h + 16*(ep+2) + s  (max base+255)
          #pragma unroll
          for (int k=0;k<32;k++){
            int t = base + 128*(k>>4) + 16*(ep+2) + (k&15);
            leA[k] = leb[(size_t)t*32 + myl];
            peA[k] = *(const f32x4*)(peb + (size_t)t*4);
          }
        }
      }
      __syncthreads();
    }
  }

  __syncthreads();   // P + L2arr + scpart visible to all

  // ================= combine (wave 0) =================
  if (wv == 0){
    bool all01 = true, allf = true;
    #pragma unroll
    for (int k=0;k<16;k++){
      unsigned v = smask[k];
      all01 = all01 && (v <= 1u);
      allf  = allf  && (v == 0u || v == 0x3F800000u);
    }
    int startv;
    if (all01)      startv = ((const int*)smask)[lane];
    else if (allf)  startv = (((const unsigned*)smask)[lane] != 0u) ? 1 : 0;
    else            startv = ((const unsigned char*)smask)[lane];

    f32x4 pe0 = *(const f32x4*)peb;
    float x0 = leb[myl] + pe0.x*mytp.x + pe0.y*mytp.y + pe0.z*mytp.z + pe0.w*mytp.w;
    float v = startv ? __builtin_amdgcn_exp2f(x0*LOG2E - PSC) : 0.f;
    float L2p = 0.f;

    #pragma unroll 1
    for (int cc=0; cc<8; ++cc){
      pf[lane] = v;
      __builtin_amdgcn_wave_barrier();
      asm volatile("" ::: "memory");
      const unsigned short* Pr = P_lds + cc*4352 + lane*68;   // own row
      float q = 0.f;
      #pragma unroll
      for (int k=0;k<16;k++){
        uint2 u = *(const uint2*)(Pr + 4*k);
        f32x4 vv = *(const f32x4*)(pf + 4*k);
        q = fmaf(__uint_as_float(u.x << 16),          vv.x, q);
        q = fmaf(__uint_as_float(u.x & 0xFFFF0000u),  vv.y, q);
        q = fmaf(__uint_as_float(u.y << 16),          vv.z, q);
        q = fmaf(__uint_as_float(u.y & 0xFFFF0000u),  vv.w, q);
      }
      __builtin_amdgcn_wave_barrier();
      asm volatile("" ::: "memory");
      float S = wave_sum64(q);
      L2p += __builtin_amdgcn_logf(S);      // v_log_f32 = log2
      v = q * __builtin_amdgcn_rcpf(S);
    }
    if (lane == 0){
      float sct = ((scpart[0]+scpart[1])+(scpart[2]+scpart[3]))
                + ((scpart[4]+scpart[5])+(scpart[6]+scpart[7]));
      float l2t = ((L2arr[0]+L2arr[1])+(L2arr[2]+L2arr[3]))
                + ((L2arr[4]+L2arr[5])+(L2arr[6]+L2arr[7]));
      float logZ = LN2 * (l2t + L2p + PSC*1024.0f);
      out[b] = sct - logZ;
    }
  }
#undef CSTEP
#undef RENORM
}

extern "C" void kernel_launch(void* const* d_in, const int* in_sizes, int n_in,
                              void* d_out, int out_size, void* d_ws, size_t ws_size,
                              hipStream_t stream)
{
  patcrf_fwd<<<256, 512, 0, stream>>>(
    (const float*)d_in[0],          // label_emissions [B,S,32]
    (const float*)d_in[1],          // pattern_emissions [B,S,4]
    (const int*)d_in[2],            // y [B,S]
    (const float*)d_in[3],          // label_transitions [32,32]
    (const int*)d_in[4],            // tag2label [64]
    (const float*)d_in[5],          // tag_patterns [64,4]
    (const float*)d_in[6],          // transition_constraints [64,64]
    (const unsigned int*)d_in[7],   // start_mask [64] (repr sniffed)
    (float*)d_out);
}